// Round 2
// baseline (636.490 us; speedup 1.0000x reference)
//
#include <hip/hip_runtime.h>
#include <math.h>

typedef __bf16 bf16x8 __attribute__((ext_vector_type(8)));
typedef float f32x4 __attribute__((ext_vector_type(4)));

__device__ __forceinline__ unsigned short f2bf(float x) {
  unsigned int u = __builtin_bit_cast(unsigned int, x);
  unsigned int r = (u + 0x7fffu + ((u >> 16) & 1u)) >> 16;
  return (unsigned short)r;
}
__device__ __forceinline__ float bf2f(unsigned short u) {
  return __builtin_bit_cast(float, ((unsigned int)u) << 16);
}
__device__ __forceinline__ void async16(const void* g, void* l) {
  __builtin_amdgcn_global_load_lds(
      (const __attribute__((address_space(1))) void*)g,
      (__attribute__((address_space(3))) void*)l, 16, 0, 0);
}

// f32 -> bf16 (RNE), 8 elems/thread
__global__ __launch_bounds__(256) void cvt_bf16_k(const float* __restrict__ in,
                                                  unsigned short* __restrict__ out,
                                                  int n8) {
  const int i = blockIdx.x * 256 + threadIdx.x;
  if (i >= n8) return;
  const float4* p = (const float4*)in + (long)i * 2;
  const float4 v0 = p[0], v1 = p[1];
  alignas(16) unsigned short o[8] = {f2bf(v0.x), f2bf(v0.y), f2bf(v0.z), f2bf(v0.w),
                                     f2bf(v1.x), f2bf(v1.y), f2bf(v1.z), f2bf(v1.w)};
  *(uint4*)(out + (long)i * 8) = *(uint4*)o;
}

// rope table: tab[t*64+i] = {cos,sin}(t * 10000^(-(4i+1)/128)), t<2048, i<64
__global__ __launch_bounds__(256) void rope_tab(float2* __restrict__ tab) {
  const int id = blockIdx.x * 256 + threadIdx.x;
  const int t = id >> 6, i = id & 63;
  const float kf = 13.287712379549449f / 128.f;  // log2(10000)/128
  const float a = (float)t * exp2f(-(4.f * (float)i + 1.f) * kf);
  float s, c;
  sincosf(a, &s, &c);
  tab[id] = make_float2(c, s);
}

// C[m,n] = sum_k A[m,k]*B[n,k]; A bf16 [M,K], B bf16 [N,K], f32 accumulate.
// Grid is XCD-swizzled (nwg % 8 == 0 required; 1536 and 512 both qualify).
// MODE 0: C f32 [M,N].
// MODE 1 (qkv): n<4096 -> bf16 rows stride 4096 (q,k); n>=4096 -> V stored
//   TRANSPOSED into Vt[bh][d][t].
template <int MODE>
__global__ __launch_bounds__(256) void gemm_bf(
    const unsigned short* __restrict__ A, const unsigned short* __restrict__ B,
    void* __restrict__ Cp, unsigned short* __restrict__ Vt, int M, int N, int K) {
  __shared__ unsigned short As[128 * 32];  // 8 KiB
  __shared__ unsigned short Bs[128 * 32];  // 8 KiB
  const int tid = threadIdx.x;
  const int lane = tid & 63;
  const int w = tid >> 6;
  const int wr = w >> 1, wc = w & 1;
  const int fr = lane & 15, fq = lane >> 4;
  // XCD-aware block swizzle: contiguous tile chunk per XCD
  const int nbx = gridDim.x;
  const int nwg = nbx * (int)gridDim.y;
  int bid = (int)blockIdx.y * nbx + (int)blockIdx.x;
  bid = (bid & 7) * (nwg >> 3) + (bid >> 3);
  const long m0 = (long)(bid / nbx) * 128;
  const long n0 = (long)(bid % nbx) * 128;
  const int sr = lane >> 2, sc = (lane & 3) * 8;  // bf16: 16 rows/call
  f32x4 acc[4][4] = {};
  for (int k0 = 0; k0 < K; k0 += 32) {
    __syncthreads();
#pragma unroll
    for (int i = 0; i < 2; i++) {
      const int r = (w * 2 + i) * 16 + sr;
      async16(A + (m0 + r) * (long)K + k0 + sc, &As[(w * 2 + i) * 512]);
      async16(B + (n0 + r) * (long)K + k0 + sc, &Bs[(w * 2 + i) * 512]);
    }
    __syncthreads();
    bf16x8 a[4], b[4];
#pragma unroll
    for (int i = 0; i < 4; i++)
      a[i] = *(const bf16x8*)&As[(wr * 64 + i * 16 + fr) * 32 + fq * 8];
#pragma unroll
    for (int j = 0; j < 4; j++)
      b[j] = *(const bf16x8*)&Bs[(wc * 64 + j * 16 + fr) * 32 + fq * 8];
#pragma unroll
    for (int i = 0; i < 4; i++)
#pragma unroll
      for (int j = 0; j < 4; j++)
        acc[i][j] =
            __builtin_amdgcn_mfma_f32_16x16x32_bf16(a[i], b[j], acc[i][j], 0, 0, 0);
  }
  if (MODE == 0) {
    float* C = (float*)Cp;
#pragma unroll
    for (int i = 0; i < 4; i++)
#pragma unroll
      for (int j = 0; j < 4; j++)
#pragma unroll
        for (int r = 0; r < 4; r++) {
          const long m = m0 + wr * 64 + i * 16 + fq * 4 + r;
          const long n = n0 + wc * 64 + j * 16 + fr;
          C[m * N + n] = acc[i][j][r];
        }
  } else if (n0 < 4096) {
    unsigned short* C = (unsigned short*)Cp;
#pragma unroll
    for (int i = 0; i < 4; i++)
#pragma unroll
      for (int j = 0; j < 4; j++)
#pragma unroll
        for (int r = 0; r < 4; r++) {
          const long m = m0 + wr * 64 + i * 16 + fq * 4 + r;
          const long n = n0 + wc * 64 + j * 16 + fr;
          C[m * 4096 + n] = f2bf(acc[i][j][r]);
        }
  } else {
    const long vb = ((m0 >> 11) * 16 + ((n0 - 4096) >> 7)) * (128L * 2048);
#pragma unroll
    for (int i = 0; i < 4; i++)
#pragma unroll
      for (int j = 0; j < 4; j++) {
        const int d = wc * 64 + j * 16 + fr;
        const int t = (int)(m0 & 2047) + wr * 64 + i * 16 + fq * 4;
        alignas(8) unsigned short o[4] = {f2bf(acc[i][j][0]), f2bf(acc[i][j][1]),
                                          f2bf(acc[i][j][2]), f2bf(acc[i][j][3])};
        *(uint2*)&Vt[vb + (long)d * 2048 + t] = *(uint2*)o;
      }
  }
}

// in-place on bf16 q,k rows (stride 4096): RMSNorm (g f32) + RoPE via table
__global__ __launch_bounds__(256) void rms_rope(unsigned short* __restrict__ qkv,
                                                const float* __restrict__ g,
                                                const float2* __restrict__ tab) {
  const int m = blockIdx.x;  // 0..4095
  const int t = m & 2047;
  const int tid = threadIdx.x;
  const int lane = tid & 63, w = tid >> 6;
  unsigned short* row = qkv + (long)m * 4096;
  const int base = tid * 8;
  alignas(16) unsigned short qs[8], ks[8];
  *(uint4*)qs = *(const uint4*)(row + base);
  *(uint4*)ks = *(const uint4*)(row + 2048 + base);
  float qv[8], kv[8];
  float sq = 0.f, sk = 0.f;
#pragma unroll
  for (int j = 0; j < 8; j++) {
    qv[j] = bf2f(qs[j]);
    kv[j] = bf2f(ks[j]);
    sq += qv[j] * qv[j];
    sk += kv[j] * kv[j];
  }
#pragma unroll
  for (int off = 1; off < 64; off <<= 1) {
    sq += __shfl_xor(sq, off);
    sk += __shfl_xor(sk, off);
  }
  __shared__ float red[2][4];
  if (lane == 0) {
    red[0][w] = sq;
    red[1][w] = sk;
  }
  __syncthreads();
  sq = red[0][0] + red[0][1] + red[0][2] + red[0][3];
  sk = red[1][0] + red[1][1] + red[1][2] + red[1][3];
  const float rq = rsqrtf(sq * (1.f / 2048.f) + 1e-6f);
  const float rk = rsqrtf(sk * (1.f / 2048.f) + 1e-6f);
  float qn[8], kn[8];
#pragma unroll
  for (int j = 0; j < 8; j++) {
    const float gg = g[base + j];
    qn[j] = qv[j] * rq * gg;
    kn[j] = kv[j] * rk * gg;
  }
  const float2* tp = tab + t * 64 + (base & 63);
  alignas(16) unsigned short qo[8], ko[8];
#pragma unroll
  for (int p = 0; p < 8; p += 2) {
    const float2 cs0 = tp[p];
    const float2 cs1 = tp[p + 1];
    qo[p] = f2bf(qn[p] * cs0.x - qn[p + 1] * cs0.y);
    qo[p + 1] = f2bf(qn[p + 1] * cs1.x + qn[p] * cs1.y);
    ko[p] = f2bf(kn[p] * cs0.x - kn[p + 1] * cs0.y);
    ko[p + 1] = f2bf(kn[p + 1] * cs1.x + kn[p] * cs1.y);
  }
  *(uint4*)(row + base) = *(uint4*)qo;
  *(uint4*)(row + 2048 + base) = *(uint4*)ko;
}

// flash attention, no K/V LDS staging: MFMA operands are wave-invariant, so
// K tile (16K) + V^T tile (16K) live in L1/L2; only per-wave P goes through
// LDS (XOR-swizzled). NO barriers in the kt loop -> waves fully decoupled.
// 1D grid 1024: bid&7 selects XCD group (4 bh per XCD -> L2-resident K/V),
// qt = slot&1 ? 31-j : j balances causal work across a CU's resident blocks.
__global__ __launch_bounds__(256, 4) void attn64(
    const unsigned short* __restrict__ QKV, const unsigned short* __restrict__ VT,
    unsigned short* __restrict__ Y) {
  const int bid = blockIdx.x;
  const int r_ = bid & 7, s_ = bid >> 3;
  const int slot = s_ >> 5, j = s_ & 31;
  const int bh = r_ * 4 + slot;
  const int qt = (slot & 1) ? (31 - j) : j;
  const int b = bh >> 4, h = bh & 15;
  const int tid = threadIdx.x, lane = tid & 63, w = tid >> 6;
  const int fr = lane & 15, fq = lane >> 4;
  __shared__ unsigned short Pl[4][16 * 64];  // 8 KiB, per-wave, XOR-swizzled
  char* Pb = (char*)&Pl[w][0];
  const long tokbase = (long)b * 2048;
  const unsigned short* Qp = QKV + tokbase * 4096 + h * 128;
  const unsigned short* Kp = Qp + 2048;
  const unsigned short* Vg = VT + (long)bh * (128 * 2048);
  const int qbase = qt * 64;
  bf16x8 aq[4];
  {
    const unsigned short* qp = Qp + (long)(qbase + w * 16 + fr) * 4096 + fq * 8;
#pragma unroll
    for (int ks = 0; ks < 4; ks++) aq[ks] = *(const bf16x8*)(qp + ks * 32);
  }
  float m_i[4], l_i[4];
#pragma unroll
  for (int r = 0; r < 4; r++) {
    m_i[r] = -1e30f;
    l_i[r] = 0.f;
  }
  f32x4 accO[8] = {};
  const float scale = 0.08838834764831845f;  // 1/sqrt(128)
  for (int kt = 0; kt <= qt; kt++) {
    f32x4 accS[4] = {};
    const unsigned short* kb = Kp + (long)(kt * 64 + fr) * 4096 + fq * 8;
#pragma unroll
    for (int n = 0; n < 4; n++)
#pragma unroll
      for (int ks = 0; ks < 4; ks++) {
        bf16x8 bk = *(const bf16x8*)(kb + (long)n * 65536 + ks * 32);
        accS[n] = __builtin_amdgcn_mfma_f32_16x16x32_bf16(aq[ks], bk, accS[n], 0, 0, 0);
      }
    if (kt == qt) {  // causal mask only needed on the diagonal tile
#pragma unroll
      for (int n = 0; n < 4; n++)
#pragma unroll
        for (int r = 0; r < 4; r++) {
          const int key = kt * 64 + n * 16 + fr;
          const int qq = qbase + w * 16 + fq * 4 + r;
          accS[n][r] = (key > qq) ? -1e30f : accS[n][r] * scale;
        }
    } else {
#pragma unroll
      for (int n = 0; n < 4; n++)
#pragma unroll
        for (int r = 0; r < 4; r++) accS[n][r] *= scale;
    }
    float mx[4];
    bool need = false;
#pragma unroll
    for (int r = 0; r < 4; r++) {
      float m = fmaxf(fmaxf(accS[0][r], accS[1][r]), fmaxf(accS[2][r], accS[3][r]));
#pragma unroll
      for (int off = 1; off < 16; off <<= 1) m = fmaxf(m, __shfl_xor(m, off));
      mx[r] = m;
      need |= (m > m_i[r] + 8.f);
    }
    if (__any(need)) {  // defer-max: rescale only when max grew materially
#pragma unroll
      for (int r = 0; r < 4; r++) {
        const float mnew = fmaxf(m_i[r], mx[r]);
        const float alpha = __expf(m_i[r] - mnew);
        m_i[r] = mnew;
        l_i[r] *= alpha;
#pragma unroll
        for (int ds = 0; ds < 8; ds++) accO[ds][r] *= alpha;
      }
    }
#pragma unroll
    for (int n = 0; n < 4; n++)
#pragma unroll
      for (int r = 0; r < 4; r++) accS[n][r] = __expf(accS[n][r] - m_i[r]);
#pragma unroll
    for (int r = 0; r < 4; r++) {
      float sum = accS[0][r] + accS[1][r] + accS[2][r] + accS[3][r];
#pragma unroll
      for (int off = 1; off < 16; off <<= 1) sum += __shfl_xor(sum, off);
      l_i[r] += sum;
    }
    // P (C/D layout) -> per-wave LDS (swizzled), no cross-wave sync needed
#pragma unroll
    for (int n = 0; n < 4; n++)
#pragma unroll
      for (int r = 0; r < 4; r++) {
        const int row = fq * 4 + r;
        const int byte = row * 128 + ((n * 32 + fr * 2) ^ ((row & 7) << 4));
        *(unsigned short*)(Pb + byte) = f2bf(accS[n][r]);
      }
#pragma unroll
    for (int ks = 0; ks < 2; ks++) {
      bf16x8 ap =
          *(const bf16x8*)(Pb + fr * 128 + ((ks * 64 + fq * 16) ^ ((fr & 7) << 4)));
#pragma unroll
      for (int ds = 0; ds < 8; ds++) {
        bf16x8 bv = *(const bf16x8*)(Vg + (long)(ds * 16 + fr) * 2048 + kt * 64 +
                                     ks * 32 + fq * 8);
        accO[ds] = __builtin_amdgcn_mfma_f32_16x16x32_bf16(ap, bv, accO[ds], 0, 0, 0);
      }
    }
  }
#pragma unroll
  for (int r = 0; r < 4; r++) l_i[r] = 1.f / l_i[r];
#pragma unroll
  for (int ds = 0; ds < 8; ds++)
#pragma unroll
    for (int r = 0; r < 4; r++) {
      const long trow = tokbase + qbase + w * 16 + fq * 4 + r;
      Y[trow * 2048 + h * 128 + ds * 16 + fr] = f2bf(accO[ds][r] * l_i[r]);
    }
}

extern "C" void kernel_launch(void* const* d_in, const int* in_sizes, int n_in,
                              void* d_out, int out_size, void* d_ws, size_t ws_size,
                              hipStream_t stream) {
  (void)out_size;
  (void)ws_size;
  const float *x = 0, *Wq = 0, *Wp = 0, *g = 0;
  for (int i = 0; i < n_in; i++) {
    switch (in_sizes[i]) {
      case 8388608: x = (const float*)d_in[i]; break;    // [2,2048,2048]
      case 12582912: Wq = (const float*)d_in[i]; break;  // [6144,2048]
      case 4194304: Wp = (const float*)d_in[i]; break;   // [2048,2048]
      case 2048: g = (const float*)d_in[i]; break;       // [2048]
    }
  }
  if (!x) x = (const float*)d_in[0];
  if (!Wq) Wq = (const float*)d_in[1];
  if (!Wp) Wp = (const float*)d_in[2];
  if (!g) g = (const float*)d_in[3];
  float* out = (float*)d_out;
  char* ws = (char*)d_ws;
  // workspace layout (97 MiB total):
  //   [0,32Mi)    qkv16: q,k rows bf16, stride 4096
  //   [32,48Mi)   VtG: V transposed [32 bh][128 d][2048 t] bf16
  //   [48,64Mi)   Y (xb lives here first; dead before attn writes Y)
  //   [64,88Mi)   Wqb bf16; [88,96Mi) Wpb bf16; [96,97Mi) rope table
  unsigned short* qkv16 = (unsigned short*)ws;
  unsigned short* VtG = (unsigned short*)(ws + 33554432);
  unsigned short* Y = (unsigned short*)(ws + 50331648);
  unsigned short* xb = Y;
  unsigned short* Wqb = (unsigned short*)(ws + 67108864);
  unsigned short* Wpb = (unsigned short*)(ws + 92274688);
  float2* tab = (float2*)(ws + 100663296);

  cvt_bf16_k<<<4096, 256, 0, stream>>>(x, xb, 1048576);
  cvt_bf16_k<<<6144, 256, 0, stream>>>(Wq, Wqb, 1572864);
  cvt_bf16_k<<<2048, 256, 0, stream>>>(Wp, Wpb, 524288);
  rope_tab<<<512, 256, 0, stream>>>(tab);
  gemm_bf<1><<<dim3(48, 32), 256, 0, stream>>>(xb, Wqb, qkv16, VtG, 4096, 6144,
                                               2048);
  rms_rope<<<4096, 256, 0, stream>>>(qkv16, g, tab);
  attn64<<<1024, 256, 0, stream>>>(qkv16, VtG, Y);  // overwrites xb (dead)
  gemm_bf<0><<<dim3(16, 32), 256, 0, stream>>>(Y, Wpb, out, nullptr, 4096, 2048,
                                               2048);
}

// Round 3
// 443.393 us; speedup vs baseline: 1.4355x; 1.4355x over previous
//
#include <hip/hip_runtime.h>
#include <math.h>

typedef __bf16 bf16x8 __attribute__((ext_vector_type(8)));
typedef float f32x4 __attribute__((ext_vector_type(4)));

__device__ __forceinline__ unsigned short f2bf(float x) {
  unsigned int u = __builtin_bit_cast(unsigned int, x);
  unsigned int r = (u + 0x7fffu + ((u >> 16) & 1u)) >> 16;
  return (unsigned short)r;
}
__device__ __forceinline__ float bf2f(unsigned short u) {
  return __builtin_bit_cast(float, ((unsigned int)u) << 16);
}
__device__ __forceinline__ void async16(const void* g, void* l) {
  __builtin_amdgcn_global_load_lds(
      (const __attribute__((address_space(1))) void*)g,
      (__attribute__((address_space(3))) void*)l, 16, 0, 0);
}

// f32 -> bf16 (RNE), 8 elems/thread
__global__ __launch_bounds__(256) void cvt_bf16_k(const float* __restrict__ in,
                                                  unsigned short* __restrict__ out,
                                                  int n8) {
  const int i = blockIdx.x * 256 + threadIdx.x;
  if (i >= n8) return;
  const float4* p = (const float4*)in + (long)i * 2;
  const float4 v0 = p[0], v1 = p[1];
  alignas(16) unsigned short o[8] = {f2bf(v0.x), f2bf(v0.y), f2bf(v0.z), f2bf(v0.w),
                                     f2bf(v1.x), f2bf(v1.y), f2bf(v1.z), f2bf(v1.w)};
  *(uint4*)(out + (long)i * 8) = *(uint4*)o;
}

// rope table: tab[t*64+i] = {cos,sin}(t * 10000^(-(4i+1)/128)), t<2048, i<64
__global__ __launch_bounds__(256) void rope_tab(float2* __restrict__ tab) {
  const int id = blockIdx.x * 256 + threadIdx.x;
  const int t = id >> 6, i = id & 63;
  const float kf = 13.287712379549449f / 128.f;  // log2(10000)/128
  const float a = (float)t * exp2f(-(4.f * (float)i + 1.f) * kf);
  float s, c;
  sincosf(a, &s, &c);
  tab[id] = make_float2(c, s);
}

// C[m,n] = sum_k A[m,k]*B[n,k]; A bf16 [M,K], B bf16 [N,K], f32 accumulate.
// Grid is XCD-swizzled (nwg % 8 == 0 required; 1536 and 512 both qualify).
// MODE 0: C f32 [M,N].
// MODE 1 (qkv): n<4096 -> bf16 rows stride 4096 (q,k); n>=4096 -> V stored
//   TRANSPOSED into Vt[bh][d][t].
template <int MODE>
__global__ __launch_bounds__(256) void gemm_bf(
    const unsigned short* __restrict__ A, const unsigned short* __restrict__ B,
    void* __restrict__ Cp, unsigned short* __restrict__ Vt, int M, int N, int K) {
  __shared__ unsigned short As[128 * 32];  // 8 KiB
  __shared__ unsigned short Bs[128 * 32];  // 8 KiB
  const int tid = threadIdx.x;
  const int lane = tid & 63;
  const int w = tid >> 6;
  const int wr = w >> 1, wc = w & 1;
  const int fr = lane & 15, fq = lane >> 4;
  // XCD-aware block swizzle: contiguous tile chunk per XCD
  const int nbx = gridDim.x;
  const int nwg = nbx * (int)gridDim.y;
  int bid = (int)blockIdx.y * nbx + (int)blockIdx.x;
  bid = (bid & 7) * (nwg >> 3) + (bid >> 3);
  const long m0 = (long)(bid / nbx) * 128;
  const long n0 = (long)(bid % nbx) * 128;
  const int sr = lane >> 2, sc = (lane & 3) * 8;  // bf16: 16 rows/call
  f32x4 acc[4][4] = {};
  for (int k0 = 0; k0 < K; k0 += 32) {
    __syncthreads();
#pragma unroll
    for (int i = 0; i < 2; i++) {
      const int r = (w * 2 + i) * 16 + sr;
      async16(A + (m0 + r) * (long)K + k0 + sc, &As[(w * 2 + i) * 512]);
      async16(B + (n0 + r) * (long)K + k0 + sc, &Bs[(w * 2 + i) * 512]);
    }
    __syncthreads();
    bf16x8 a[4], b[4];
#pragma unroll
    for (int i = 0; i < 4; i++)
      a[i] = *(const bf16x8*)&As[(wr * 64 + i * 16 + fr) * 32 + fq * 8];
#pragma unroll
    for (int j = 0; j < 4; j++)
      b[j] = *(const bf16x8*)&Bs[(wc * 64 + j * 16 + fr) * 32 + fq * 8];
#pragma unroll
    for (int i = 0; i < 4; i++)
#pragma unroll
      for (int j = 0; j < 4; j++)
        acc[i][j] =
            __builtin_amdgcn_mfma_f32_16x16x32_bf16(a[i], b[j], acc[i][j], 0, 0, 0);
  }
  if (MODE == 0) {
    float* C = (float*)Cp;
#pragma unroll
    for (int i = 0; i < 4; i++)
#pragma unroll
      for (int j = 0; j < 4; j++)
#pragma unroll
        for (int r = 0; r < 4; r++) {
          const long m = m0 + wr * 64 + i * 16 + fq * 4 + r;
          const long n = n0 + wc * 64 + j * 16 + fr;
          C[m * N + n] = acc[i][j][r];
        }
  } else if (n0 < 4096) {
    unsigned short* C = (unsigned short*)Cp;
#pragma unroll
    for (int i = 0; i < 4; i++)
#pragma unroll
      for (int j = 0; j < 4; j++)
#pragma unroll
        for (int r = 0; r < 4; r++) {
          const long m = m0 + wr * 64 + i * 16 + fq * 4 + r;
          const long n = n0 + wc * 64 + j * 16 + fr;
          C[m * 4096 + n] = f2bf(acc[i][j][r]);
        }
  } else {
    const long vb = ((m0 >> 11) * 16 + ((n0 - 4096) >> 7)) * (128L * 2048);
#pragma unroll
    for (int i = 0; i < 4; i++)
#pragma unroll
      for (int j = 0; j < 4; j++) {
        const int d = wc * 64 + j * 16 + fr;
        const int t = (int)(m0 & 2047) + wr * 64 + i * 16 + fq * 4;
        alignas(8) unsigned short o[4] = {f2bf(acc[i][j][0]), f2bf(acc[i][j][1]),
                                          f2bf(acc[i][j][2]), f2bf(acc[i][j][3])};
        *(uint2*)&Vt[vb + (long)d * 2048 + t] = *(uint2*)o;
      }
  }
}

// in-place on bf16 q,k rows (stride 4096): RMSNorm (g f32) + RoPE via table
__global__ __launch_bounds__(256) void rms_rope(unsigned short* __restrict__ qkv,
                                                const float* __restrict__ g,
                                                const float2* __restrict__ tab) {
  const int m = blockIdx.x;  // 0..4095
  const int t = m & 2047;
  const int tid = threadIdx.x;
  const int lane = tid & 63, w = tid >> 6;
  unsigned short* row = qkv + (long)m * 4096;
  const int base = tid * 8;
  alignas(16) unsigned short qs[8], ks[8];
  *(uint4*)qs = *(const uint4*)(row + base);
  *(uint4*)ks = *(const uint4*)(row + 2048 + base);
  float qv[8], kv[8];
  float sq = 0.f, sk = 0.f;
#pragma unroll
  for (int j = 0; j < 8; j++) {
    qv[j] = bf2f(qs[j]);
    kv[j] = bf2f(ks[j]);
    sq += qv[j] * qv[j];
    sk += kv[j] * kv[j];
  }
#pragma unroll
  for (int off = 1; off < 64; off <<= 1) {
    sq += __shfl_xor(sq, off);
    sk += __shfl_xor(sk, off);
  }
  __shared__ float red[2][4];
  if (lane == 0) {
    red[0][w] = sq;
    red[1][w] = sk;
  }
  __syncthreads();
  sq = red[0][0] + red[0][1] + red[0][2] + red[0][3];
  sk = red[1][0] + red[1][1] + red[1][2] + red[1][3];
  const float rq = rsqrtf(sq * (1.f / 2048.f) + 1e-6f);
  const float rk = rsqrtf(sk * (1.f / 2048.f) + 1e-6f);
  float qn[8], kn[8];
#pragma unroll
  for (int j = 0; j < 8; j++) {
    const float gg = g[base + j];
    qn[j] = qv[j] * rq * gg;
    kn[j] = kv[j] * rk * gg;
  }
  const float2* tp = tab + t * 64 + (base & 63);
  alignas(16) unsigned short qo[8], ko[8];
#pragma unroll
  for (int p = 0; p < 8; p += 2) {
    const float2 cs0 = tp[p];
    const float2 cs1 = tp[p + 1];
    qo[p] = f2bf(qn[p] * cs0.x - qn[p + 1] * cs0.y);
    qo[p + 1] = f2bf(qn[p + 1] * cs1.x + qn[p] * cs1.y);
    ko[p] = f2bf(kn[p] * cs0.x - kn[p + 1] * cs0.y);
    ko[p + 1] = f2bf(kn[p + 1] * cs1.x + kn[p] * cs1.y);
  }
  *(uint4*)(row + base) = *(uint4*)qo;
  *(uint4*)(row + 2048 + base) = *(uint4*)ko;
}

// flash attention, 2-phase counted-vmcnt pipeline:
//   K,V double-buffered in LDS, staged via global_load_lds with PRE-SWIZZLED
//   global source (linear LDS dest, G21); reads XOR-swizzle (row&7)<<3 elems
//   -> conflict-free without padding. Next tile's 8 loads issue BEFORE compute;
//   s_waitcnt vmcnt(8) + raw s_barrier (never drain to 0 in-loop) hides the
//   staging latency under QK+softmax+PV. Per-wave P in LDS (no sync).
// Grid 1024 1D: bid&7 pins 4 bh per XCD (L2-resident K/V, FETCH 125->30MB);
// qt = slot&1 ? 31-j : j balances causal work.
__global__ __launch_bounds__(256, 2) void attn64(
    const unsigned short* __restrict__ QKV, const unsigned short* __restrict__ VT,
    unsigned short* __restrict__ Y) {
  const int bid = blockIdx.x;
  const int r_ = bid & 7, s_ = bid >> 3;
  const int slot = s_ >> 5, j = s_ & 31;
  const int bh = r_ * 4 + slot;
  const int qt = (slot & 1) ? (31 - j) : j;
  const int b = bh >> 4, h = bh & 15;
  const int tid = threadIdx.x, lane = tid & 63, w = tid >> 6;
  const int fr = lane & 15, fq = lane >> 4;
  __shared__ unsigned short Kl[2][64 * 128];   // 2 x 16 KiB, swizzled content
  __shared__ unsigned short Vl[2][128 * 64];   // 2 x 16 KiB, V^T [d][tok]
  __shared__ unsigned short Pl[4][16 * 64];    // 8 KiB per-wave P
  char* Pb = (char*)&Pl[w][0];
  const long tokbase = (long)b * 2048;
  const unsigned short* Qp = QKV + tokbase * 4096 + h * 128;
  const unsigned short* Kp = Qp + 2048;
  const unsigned short* Vg = VT + (long)bh * (128 * 2048);
  const int qbase = qt * 64;
  bf16x8 aq[4];
  {
    const unsigned short* qp = Qp + (long)(qbase + w * 16 + fr) * 4096 + fq * 8;
#pragma unroll
    for (int ks = 0; ks < 4; ks++) aq[ks] = *(const bf16x8*)(qp + ks * 32);
  }
  // stage one K+V tile (8 async16/wave): linear LDS dest, inverse-swizzled src
  const int lH = lane >> 4, lL = (lane & 15) * 8;  // K map: 16B x 16 lanes/row
  const int vH = lane >> 3, vL = (lane & 7) * 8;   // V map: 16B x 8 lanes/row
  auto stage = [&](unsigned short* Kd, unsigned short* Vd, int kt) {
#pragma unroll
    for (int i = 0; i < 4; i++) {
      const int rowK = w * 4 + i * 16 + lH;
      async16(Kp + (long)(kt * 64 + rowK) * 4096 + (lL ^ ((rowK & 7) << 3)),
              Kd + w * 512 + i * 2048);
      const int rowV = w * 8 + i * 32 + vH;
      async16(Vg + (long)rowV * 2048 + kt * 64 + (vL ^ ((rowV & 7) << 3)),
              Vd + w * 512 + i * 2048);
    }
  };
  float m_i[4], l_i[4];
#pragma unroll
  for (int r = 0; r < 4; r++) {
    m_i[r] = -1e30f;
    l_i[r] = 0.f;
  }
  f32x4 accO[8] = {};
  const float scale = 0.08838834764831845f;  // 1/sqrt(128)
  int cur = 0;
  stage(Kl[0], Vl[0], 0);
  for (int kt = 0; kt <= qt; kt++) {
    if (kt < qt) {
      stage(Kl[cur ^ 1], Vl[cur ^ 1], kt + 1);  // prefetch next tile
      asm volatile("s_waitcnt vmcnt(8)" ::: "memory");  // cur tile staged; 8 in flight
    } else {
      asm volatile("s_waitcnt vmcnt(0)" ::: "memory");
    }
    __builtin_amdgcn_s_barrier();
    asm volatile("" ::: "memory");
    const unsigned short* Kc = Kl[cur];
    const unsigned short* Vc = Vl[cur];
    f32x4 accS[4] = {};
#pragma unroll
    for (int n = 0; n < 4; n++) {
      const int rowK = n * 16 + fr;
#pragma unroll
      for (int ks = 0; ks < 4; ks++) {
        bf16x8 bk =
            *(const bf16x8*)&Kc[rowK * 128 + ((ks * 32 + fq * 8) ^ ((fr & 7) << 3))];
        accS[n] = __builtin_amdgcn_mfma_f32_16x16x32_bf16(aq[ks], bk, accS[n], 0, 0, 0);
      }
    }
    if (kt == qt) {  // causal mask only needed on the diagonal tile
#pragma unroll
      for (int n = 0; n < 4; n++)
#pragma unroll
        for (int r = 0; r < 4; r++) {
          const int key = kt * 64 + n * 16 + fr;
          const int qq = qbase + w * 16 + fq * 4 + r;
          accS[n][r] = (key > qq) ? -1e30f : accS[n][r] * scale;
        }
    } else {
#pragma unroll
      for (int n = 0; n < 4; n++)
#pragma unroll
        for (int r = 0; r < 4; r++) accS[n][r] *= scale;
    }
    float mx[4];
    bool need = false;
#pragma unroll
    for (int r = 0; r < 4; r++) {
      float m = fmaxf(fmaxf(accS[0][r], accS[1][r]), fmaxf(accS[2][r], accS[3][r]));
#pragma unroll
      for (int off = 1; off < 16; off <<= 1) m = fmaxf(m, __shfl_xor(m, off));
      mx[r] = m;
      need |= (m > m_i[r] + 8.f);
    }
    if (__any(need)) {  // defer-max: rescale only when max grew materially
#pragma unroll
      for (int r = 0; r < 4; r++) {
        const float mnew = fmaxf(m_i[r], mx[r]);
        const float alpha = __expf(m_i[r] - mnew);
        m_i[r] = mnew;
        l_i[r] *= alpha;
#pragma unroll
        for (int ds = 0; ds < 8; ds++) accO[ds][r] *= alpha;
      }
    }
#pragma unroll
    for (int n = 0; n < 4; n++)
#pragma unroll
      for (int r = 0; r < 4; r++) accS[n][r] = __expf(accS[n][r] - m_i[r]);
#pragma unroll
    for (int r = 0; r < 4; r++) {
      float sum = accS[0][r] + accS[1][r] + accS[2][r] + accS[3][r];
#pragma unroll
      for (int off = 1; off < 16; off <<= 1) sum += __shfl_xor(sum, off);
      l_i[r] += sum;
    }
    // P (C/D layout) -> per-wave LDS (swizzled), no cross-wave sync needed
#pragma unroll
    for (int n = 0; n < 4; n++)
#pragma unroll
      for (int r = 0; r < 4; r++) {
        const int row = fq * 4 + r;
        const int byte = row * 128 + ((n * 32 + fr * 2) ^ ((row & 7) << 4));
        *(unsigned short*)(Pb + byte) = f2bf(accS[n][r]);
      }
#pragma unroll
    for (int ks = 0; ks < 2; ks++) {
      bf16x8 ap =
          *(const bf16x8*)(Pb + fr * 128 + ((ks * 64 + fq * 16) ^ ((fr & 7) << 4)));
#pragma unroll
      for (int ds = 0; ds < 8; ds++) {
        bf16x8 bv = *(const bf16x8*)&Vc[(ds * 16 + fr) * 64 +
                                        ((ks * 32 + fq * 8) ^ ((fr & 7) << 3))];
        accO[ds] = __builtin_amdgcn_mfma_f32_16x16x32_bf16(ap, bv, accO[ds], 0, 0, 0);
      }
    }
    asm volatile("" ::: "memory");
    __builtin_amdgcn_s_barrier();  // all reads of buf[cur] done -> safe to overwrite
    asm volatile("" ::: "memory");
    cur ^= 1;
  }
#pragma unroll
  for (int r = 0; r < 4; r++) l_i[r] = 1.f / l_i[r];
#pragma unroll
  for (int ds = 0; ds < 8; ds++)
#pragma unroll
    for (int r = 0; r < 4; r++) {
      const long trow = tokbase + qbase + w * 16 + fq * 4 + r;
      Y[trow * 2048 + h * 128 + ds * 16 + fr] = f2bf(accO[ds][r] * l_i[r]);
    }
}

extern "C" void kernel_launch(void* const* d_in, const int* in_sizes, int n_in,
                              void* d_out, int out_size, void* d_ws, size_t ws_size,
                              hipStream_t stream) {
  (void)out_size;
  (void)ws_size;
  const float *x = 0, *Wq = 0, *Wp = 0, *g = 0;
  for (int i = 0; i < n_in; i++) {
    switch (in_sizes[i]) {
      case 8388608: x = (const float*)d_in[i]; break;    // [2,2048,2048]
      case 12582912: Wq = (const float*)d_in[i]; break;  // [6144,2048]
      case 4194304: Wp = (const float*)d_in[i]; break;   // [2048,2048]
      case 2048: g = (const float*)d_in[i]; break;       // [2048]
    }
  }
  if (!x) x = (const float*)d_in[0];
  if (!Wq) Wq = (const float*)d_in[1];
  if (!Wp) Wp = (const float*)d_in[2];
  if (!g) g = (const float*)d_in[3];
  float* out = (float*)d_out;
  char* ws = (char*)d_ws;
  // workspace layout (97 MiB total):
  //   [0,32Mi)    qkv16: q,k rows bf16, stride 4096
  //   [32,48Mi)   VtG: V transposed [32 bh][128 d][2048 t] bf16
  //   [48,64Mi)   Y (xb lives here first; dead before attn writes Y)
  //   [64,88Mi)   Wqb bf16; [88,96Mi) Wpb bf16; [96,97Mi) rope table
  unsigned short* qkv16 = (unsigned short*)ws;
  unsigned short* VtG = (unsigned short*)(ws + 33554432);
  unsigned short* Y = (unsigned short*)(ws + 50331648);
  unsigned short* xb = Y;
  unsigned short* Wqb = (unsigned short*)(ws + 67108864);
  unsigned short* Wpb = (unsigned short*)(ws + 92274688);
  float2* tab = (float2*)(ws + 100663296);

  cvt_bf16_k<<<4096, 256, 0, stream>>>(x, xb, 1048576);
  cvt_bf16_k<<<6144, 256, 0, stream>>>(Wq, Wqb, 1572864);
  cvt_bf16_k<<<2048, 256, 0, stream>>>(Wp, Wpb, 524288);
  rope_tab<<<512, 256, 0, stream>>>(tab);
  gemm_bf<1><<<dim3(48, 32), 256, 0, stream>>>(xb, Wqb, qkv16, VtG, 4096, 6144,
                                               2048);
  rms_rope<<<4096, 256, 0, stream>>>(qkv16, g, tab);
  attn64<<<1024, 256, 0, stream>>>(qkv16, VtG, Y);  // overwrites xb (dead)
  gemm_bf<0><<<dim3(16, 32), 256, 0, stream>>>(Y, Wpb, out, nullptr, 4096, 2048,
                                               2048);
}

// Round 4
// 424.909 us; speedup vs baseline: 1.4979x; 1.0435x over previous
//
#include <hip/hip_runtime.h>
#include <math.h>

typedef __bf16 bf16x8 __attribute__((ext_vector_type(8)));
typedef float f32x4 __attribute__((ext_vector_type(4)));

__device__ __forceinline__ unsigned short f2bf(float x) {
  unsigned int u = __builtin_bit_cast(unsigned int, x);
  unsigned int r = (u + 0x7fffu + ((u >> 16) & 1u)) >> 16;
  return (unsigned short)r;
}
__device__ __forceinline__ float bf2f(unsigned short u) {
  return __builtin_bit_cast(float, ((unsigned int)u) << 16);
}
__device__ __forceinline__ void async16(const void* g, void* l) {
  __builtin_amdgcn_global_load_lds(
      (const __attribute__((address_space(1))) void*)g,
      (__attribute__((address_space(3))) void*)l, 16, 0, 0);
}

// f32 -> bf16 (RNE), 8 elems/thread
__global__ __launch_bounds__(256) void cvt_bf16_k(const float* __restrict__ in,
                                                  unsigned short* __restrict__ out,
                                                  int n8) {
  const int i = blockIdx.x * 256 + threadIdx.x;
  if (i >= n8) return;
  const float4* p = (const float4*)in + (long)i * 2;
  const float4 v0 = p[0], v1 = p[1];
  alignas(16) unsigned short o[8] = {f2bf(v0.x), f2bf(v0.y), f2bf(v0.z), f2bf(v0.w),
                                     f2bf(v1.x), f2bf(v1.y), f2bf(v1.z), f2bf(v1.w)};
  *(uint4*)(out + (long)i * 8) = *(uint4*)o;
}

// rope table: tab[t*64+i] = {cos,sin}(t * 10000^(-(4i+1)/128)), t<2048, i<64
__global__ __launch_bounds__(256) void rope_tab(float2* __restrict__ tab) {
  const int id = blockIdx.x * 256 + threadIdx.x;
  const int t = id >> 6, i = id & 63;
  const float kf = 13.287712379549449f / 128.f;  // log2(10000)/128
  const float a = (float)t * exp2f(-(4.f * (float)i + 1.f) * kf);
  float s, c;
  sincosf(a, &s, &c);
  tab[id] = make_float2(c, s);
}

// C[m,n] = sum_k A[m,k]*B[n,k]; A bf16 [M,K], B bf16 [N,K], f32 accumulate.
// 2-phase counted-vmcnt pipeline (same pattern as attn64 below, validated R3):
// double-buffered As/Bs, next K-tile's 4 global_load_lds issued BEFORE compute,
// s_waitcnt vmcnt(4) + raw s_barrier -> 4 prefetch loads stay in flight across
// the barrier; never drain to 0 in-loop.
// Grid is XCD-swizzled (nwg % 8 == 0 required; 1536 and 512 both qualify).
// MODE 0: C f32 [M,N].
// MODE 1 (qkv): n<4096 -> bf16 rows stride 4096 (q,k); n>=4096 -> V stored
//   TRANSPOSED into Vt[bh][d][t].
template <int MODE>
__global__ __launch_bounds__(256) void gemm_bf(
    const unsigned short* __restrict__ A, const unsigned short* __restrict__ B,
    void* __restrict__ Cp, unsigned short* __restrict__ Vt, int M, int N, int K) {
  __shared__ unsigned short As[2][128 * 32];  // 2 x 8 KiB
  __shared__ unsigned short Bs[2][128 * 32];  // 2 x 8 KiB
  const int tid = threadIdx.x;
  const int lane = tid & 63;
  const int w = tid >> 6;
  const int wr = w >> 1, wc = w & 1;
  const int fr = lane & 15, fq = lane >> 4;
  // XCD-aware block swizzle: contiguous tile chunk per XCD
  const int nbx = gridDim.x;
  const int nwg = nbx * (int)gridDim.y;
  int bid = (int)blockIdx.y * nbx + (int)blockIdx.x;
  bid = (bid & 7) * (nwg >> 3) + (bid >> 3);
  const long m0 = (long)(bid / nbx) * 128;
  const long n0 = (long)(bid % nbx) * 128;
  const int sr = lane >> 2, sc = (lane & 3) * 8;  // bf16: 16 rows/call
  f32x4 acc[4][4] = {};
  auto stage = [&](int buf, int k0) {
#pragma unroll
    for (int i = 0; i < 2; i++) {
      const int r = (w * 2 + i) * 16 + sr;
      async16(A + (m0 + r) * (long)K + k0 + sc, &As[buf][(w * 2 + i) * 512]);
      async16(B + (n0 + r) * (long)K + k0 + sc, &Bs[buf][(w * 2 + i) * 512]);
    }
  };
  int cur = 0;
  stage(0, 0);
  for (int k0 = 0; k0 < K; k0 += 32) {
    if (k0 + 32 < K) {
      stage(cur ^ 1, k0 + 32);  // prefetch next K-tile
      asm volatile("s_waitcnt vmcnt(4)" ::: "memory");  // cur tile staged
    } else {
      asm volatile("s_waitcnt vmcnt(0)" ::: "memory");
    }
    __builtin_amdgcn_s_barrier();
    asm volatile("" ::: "memory");
    bf16x8 a[4], b[4];
#pragma unroll
    for (int i = 0; i < 4; i++)
      a[i] = *(const bf16x8*)&As[cur][(wr * 64 + i * 16 + fr) * 32 + fq * 8];
#pragma unroll
    for (int j = 0; j < 4; j++)
      b[j] = *(const bf16x8*)&Bs[cur][(wc * 64 + j * 16 + fr) * 32 + fq * 8];
#pragma unroll
    for (int i = 0; i < 4; i++)
#pragma unroll
      for (int j = 0; j < 4; j++)
        acc[i][j] =
            __builtin_amdgcn_mfma_f32_16x16x32_bf16(a[i], b[j], acc[i][j], 0, 0, 0);
    asm volatile("" ::: "memory");
    __builtin_amdgcn_s_barrier();  // all reads of buf[cur] done -> safe to overwrite
    asm volatile("" ::: "memory");
    cur ^= 1;
  }
  if (MODE == 0) {
    float* C = (float*)Cp;
#pragma unroll
    for (int i = 0; i < 4; i++)
#pragma unroll
      for (int j = 0; j < 4; j++)
#pragma unroll
        for (int r = 0; r < 4; r++) {
          const long m = m0 + wr * 64 + i * 16 + fq * 4 + r;
          const long n = n0 + wc * 64 + j * 16 + fr;
          C[m * N + n] = acc[i][j][r];
        }
  } else if (n0 < 4096) {
    unsigned short* C = (unsigned short*)Cp;
#pragma unroll
    for (int i = 0; i < 4; i++)
#pragma unroll
      for (int j = 0; j < 4; j++)
#pragma unroll
        for (int r = 0; r < 4; r++) {
          const long m = m0 + wr * 64 + i * 16 + fq * 4 + r;
          const long n = n0 + wc * 64 + j * 16 + fr;
          C[m * 4096 + n] = f2bf(acc[i][j][r]);
        }
  } else {
    const long vb = ((m0 >> 11) * 16 + ((n0 - 4096) >> 7)) * (128L * 2048);
#pragma unroll
    for (int i = 0; i < 4; i++)
#pragma unroll
      for (int j = 0; j < 4; j++) {
        const int d = wc * 64 + j * 16 + fr;
        const int t = (int)(m0 & 2047) + wr * 64 + i * 16 + fq * 4;
        alignas(8) unsigned short o[4] = {f2bf(acc[i][j][0]), f2bf(acc[i][j][1]),
                                          f2bf(acc[i][j][2]), f2bf(acc[i][j][3])};
        *(uint2*)&Vt[vb + (long)d * 2048 + t] = *(uint2*)o;
      }
  }
}

// in-place on bf16 q,k rows (stride 4096): RMSNorm (g f32) + RoPE via table
__global__ __launch_bounds__(256) void rms_rope(unsigned short* __restrict__ qkv,
                                                const float* __restrict__ g,
                                                const float2* __restrict__ tab) {
  const int m = blockIdx.x;  // 0..4095
  const int t = m & 2047;
  const int tid = threadIdx.x;
  const int lane = tid & 63, w = tid >> 6;
  unsigned short* row = qkv + (long)m * 4096;
  const int base = tid * 8;
  alignas(16) unsigned short qs[8], ks[8];
  *(uint4*)qs = *(const uint4*)(row + base);
  *(uint4*)ks = *(const uint4*)(row + 2048 + base);
  float qv[8], kv[8];
  float sq = 0.f, sk = 0.f;
#pragma unroll
  for (int j = 0; j < 8; j++) {
    qv[j] = bf2f(qs[j]);
    kv[j] = bf2f(ks[j]);
    sq += qv[j] * qv[j];
    sk += kv[j] * kv[j];
  }
#pragma unroll
  for (int off = 1; off < 64; off <<= 1) {
    sq += __shfl_xor(sq, off);
    sk += __shfl_xor(sk, off);
  }
  __shared__ float red[2][4];
  if (lane == 0) {
    red[0][w] = sq;
    red[1][w] = sk;
  }
  __syncthreads();
  sq = red[0][0] + red[0][1] + red[0][2] + red[0][3];
  sk = red[1][0] + red[1][1] + red[1][2] + red[1][3];
  const float rq = rsqrtf(sq * (1.f / 2048.f) + 1e-6f);
  const float rk = rsqrtf(sk * (1.f / 2048.f) + 1e-6f);
  float qn[8], kn[8];
#pragma unroll
  for (int j = 0; j < 8; j++) {
    const float gg = g[base + j];
    qn[j] = qv[j] * rq * gg;
    kn[j] = kv[j] * rk * gg;
  }
  const float2* tp = tab + t * 64 + (base & 63);
  alignas(16) unsigned short qo[8], ko[8];
#pragma unroll
  for (int p = 0; p < 8; p += 2) {
    const float2 cs0 = tp[p];
    const float2 cs1 = tp[p + 1];
    qo[p] = f2bf(qn[p] * cs0.x - qn[p + 1] * cs0.y);
    qo[p + 1] = f2bf(qn[p + 1] * cs1.x + qn[p] * cs1.y);
    ko[p] = f2bf(kn[p] * cs0.x - kn[p + 1] * cs0.y);
    ko[p + 1] = f2bf(kn[p + 1] * cs1.x + kn[p] * cs1.y);
  }
  *(uint4*)(row + base) = *(uint4*)qo;
  *(uint4*)(row + 2048 + base) = *(uint4*)ko;
}

// flash attention, 2-phase counted-vmcnt pipeline:
//   K,V double-buffered in LDS, staged via global_load_lds with PRE-SWIZZLED
//   global source (linear LDS dest, G21); reads XOR-swizzle (row&7)<<3 elems
//   -> conflict-free without padding. Next tile's 8 loads issue BEFORE compute;
//   s_waitcnt vmcnt(8) + raw s_barrier (never drain to 0 in-loop) hides the
//   staging latency under QK+softmax+PV. Per-wave P in LDS (no sync).
// Grid 1024 1D: bid&7 pins 4 bh per XCD (L2-resident K/V, FETCH 125->30MB);
// qt = slot&1 ? 31-j : j balances causal work.
__global__ __launch_bounds__(256, 2) void attn64(
    const unsigned short* __restrict__ QKV, const unsigned short* __restrict__ VT,
    unsigned short* __restrict__ Y) {
  const int bid = blockIdx.x;
  const int r_ = bid & 7, s_ = bid >> 3;
  const int slot = s_ >> 5, j = s_ & 31;
  const int bh = r_ * 4 + slot;
  const int qt = (slot & 1) ? (31 - j) : j;
  const int b = bh >> 4, h = bh & 15;
  const int tid = threadIdx.x, lane = tid & 63, w = tid >> 6;
  const int fr = lane & 15, fq = lane >> 4;
  __shared__ unsigned short Kl[2][64 * 128];   // 2 x 16 KiB, swizzled content
  __shared__ unsigned short Vl[2][128 * 64];   // 2 x 16 KiB, V^T [d][tok]
  __shared__ unsigned short Pl[4][16 * 64];    // 8 KiB per-wave P
  char* Pb = (char*)&Pl[w][0];
  const long tokbase = (long)b * 2048;
  const unsigned short* Qp = QKV + tokbase * 4096 + h * 128;
  const unsigned short* Kp = Qp + 2048;
  const unsigned short* Vg = VT + (long)bh * (128 * 2048);
  const int qbase = qt * 64;
  bf16x8 aq[4];
  {
    const unsigned short* qp = Qp + (long)(qbase + w * 16 + fr) * 4096 + fq * 8;
#pragma unroll
    for (int ks = 0; ks < 4; ks++) aq[ks] = *(const bf16x8*)(qp + ks * 32);
  }
  // stage one K+V tile (8 async16/wave): linear LDS dest, inverse-swizzled src
  const int lH = lane >> 4, lL = (lane & 15) * 8;  // K map: 16B x 16 lanes/row
  const int vH = lane >> 3, vL = (lane & 7) * 8;   // V map: 16B x 8 lanes/row
  auto stage = [&](unsigned short* Kd, unsigned short* Vd, int kt) {
#pragma unroll
    for (int i = 0; i < 4; i++) {
      const int rowK = w * 4 + i * 16 + lH;
      async16(Kp + (long)(kt * 64 + rowK) * 4096 + (lL ^ ((rowK & 7) << 3)),
              Kd + w * 512 + i * 2048);
      const int rowV = w * 8 + i * 32 + vH;
      async16(Vg + (long)rowV * 2048 + kt * 64 + (vL ^ ((rowV & 7) << 3)),
              Vd + w * 512 + i * 2048);
    }
  };
  float m_i[4], l_i[4];
#pragma unroll
  for (int r = 0; r < 4; r++) {
    m_i[r] = -1e30f;
    l_i[r] = 0.f;
  }
  f32x4 accO[8] = {};
  const float scale = 0.08838834764831845f;  // 1/sqrt(128)
  int cur = 0;
  stage(Kl[0], Vl[0], 0);
  for (int kt = 0; kt <= qt; kt++) {
    if (kt < qt) {
      stage(Kl[cur ^ 1], Vl[cur ^ 1], kt + 1);  // prefetch next tile
      asm volatile("s_waitcnt vmcnt(8)" ::: "memory");  // cur tile staged; 8 in flight
    } else {
      asm volatile("s_waitcnt vmcnt(0)" ::: "memory");
    }
    __builtin_amdgcn_s_barrier();
    asm volatile("" ::: "memory");
    const unsigned short* Kc = Kl[cur];
    const unsigned short* Vc = Vl[cur];
    f32x4 accS[4] = {};
#pragma unroll
    for (int n = 0; n < 4; n++) {
      const int rowK = n * 16 + fr;
#pragma unroll
      for (int ks = 0; ks < 4; ks++) {
        bf16x8 bk =
            *(const bf16x8*)&Kc[rowK * 128 + ((ks * 32 + fq * 8) ^ ((fr & 7) << 3))];
        accS[n] = __builtin_amdgcn_mfma_f32_16x16x32_bf16(aq[ks], bk, accS[n], 0, 0, 0);
      }
    }
    if (kt == qt) {  // causal mask only needed on the diagonal tile
#pragma unroll
      for (int n = 0; n < 4; n++)
#pragma unroll
        for (int r = 0; r < 4; r++) {
          const int key = kt * 64 + n * 16 + fr;
          const int qq = qbase + w * 16 + fq * 4 + r;
          accS[n][r] = (key > qq) ? -1e30f : accS[n][r] * scale;
        }
    } else {
#pragma unroll
      for (int n = 0; n < 4; n++)
#pragma unroll
        for (int r = 0; r < 4; r++) accS[n][r] *= scale;
    }
    float mx[4];
    bool need = false;
#pragma unroll
    for (int r = 0; r < 4; r++) {
      float m = fmaxf(fmaxf(accS[0][r], accS[1][r]), fmaxf(accS[2][r], accS[3][r]));
#pragma unroll
      for (int off = 1; off < 16; off <<= 1) m = fmaxf(m, __shfl_xor(m, off));
      mx[r] = m;
      need |= (m > m_i[r] + 8.f);
    }
    if (__any(need)) {  // defer-max: rescale only when max grew materially
#pragma unroll
      for (int r = 0; r < 4; r++) {
        const float mnew = fmaxf(m_i[r], mx[r]);
        const float alpha = __expf(m_i[r] - mnew);
        m_i[r] = mnew;
        l_i[r] *= alpha;
#pragma unroll
        for (int ds = 0; ds < 8; ds++) accO[ds][r] *= alpha;
      }
    }
#pragma unroll
    for (int n = 0; n < 4; n++)
#pragma unroll
      for (int r = 0; r < 4; r++) accS[n][r] = __expf(accS[n][r] - m_i[r]);
#pragma unroll
    for (int r = 0; r < 4; r++) {
      float sum = accS[0][r] + accS[1][r] + accS[2][r] + accS[3][r];
#pragma unroll
      for (int off = 1; off < 16; off <<= 1) sum += __shfl_xor(sum, off);
      l_i[r] += sum;
    }
    // P (C/D layout) -> per-wave LDS (swizzled), no cross-wave sync needed
#pragma unroll
    for (int n = 0; n < 4; n++)
#pragma unroll
      for (int r = 0; r < 4; r++) {
        const int row = fq * 4 + r;
        const int byte = row * 128 + ((n * 32 + fr * 2) ^ ((row & 7) << 4));
        *(unsigned short*)(Pb + byte) = f2bf(accS[n][r]);
      }
#pragma unroll
    for (int ks = 0; ks < 2; ks++) {
      bf16x8 ap =
          *(const bf16x8*)(Pb + fr * 128 + ((ks * 64 + fq * 16) ^ ((fr & 7) << 4)));
#pragma unroll
      for (int ds = 0; ds < 8; ds++) {
        bf16x8 bv = *(const bf16x8*)&Vc[(ds * 16 + fr) * 64 +
                                        ((ks * 32 + fq * 8) ^ ((fr & 7) << 3))];
        accO[ds] = __builtin_amdgcn_mfma_f32_16x16x32_bf16(ap, bv, accO[ds], 0, 0, 0);
      }
    }
    asm volatile("" ::: "memory");
    __builtin_amdgcn_s_barrier();  // all reads of buf[cur] done -> safe to overwrite
    asm volatile("" ::: "memory");
    cur ^= 1;
  }
#pragma unroll
  for (int r = 0; r < 4; r++) l_i[r] = 1.f / l_i[r];
#pragma unroll
  for (int ds = 0; ds < 8; ds++)
#pragma unroll
    for (int r = 0; r < 4; r++) {
      const long trow = tokbase + qbase + w * 16 + fq * 4 + r;
      Y[trow * 2048 + h * 128 + ds * 16 + fr] = f2bf(accO[ds][r] * l_i[r]);
    }
}

extern "C" void kernel_launch(void* const* d_in, const int* in_sizes, int n_in,
                              void* d_out, int out_size, void* d_ws, size_t ws_size,
                              hipStream_t stream) {
  (void)out_size;
  (void)ws_size;
  const float *x = 0, *Wq = 0, *Wp = 0, *g = 0;
  for (int i = 0; i < n_in; i++) {
    switch (in_sizes[i]) {
      case 8388608: x = (const float*)d_in[i]; break;    // [2,2048,2048]
      case 12582912: Wq = (const float*)d_in[i]; break;  // [6144,2048]
      case 4194304: Wp = (const float*)d_in[i]; break;   // [2048,2048]
      case 2048: g = (const float*)d_in[i]; break;       // [2048]
    }
  }
  if (!x) x = (const float*)d_in[0];
  if (!Wq) Wq = (const float*)d_in[1];
  if (!Wp) Wp = (const float*)d_in[2];
  if (!g) g = (const float*)d_in[3];
  float* out = (float*)d_out;
  char* ws = (char*)d_ws;
  // workspace layout (97 MiB total):
  //   [0,32Mi)    qkv16: q,k rows bf16, stride 4096
  //   [32,48Mi)   VtG: V transposed [32 bh][128 d][2048 t] bf16
  //   [48,64Mi)   Y (xb lives here first; dead before attn writes Y)
  //   [64,88Mi)   Wqb bf16; [88,96Mi) Wpb bf16; [96,97Mi) rope table
  unsigned short* qkv16 = (unsigned short*)ws;
  unsigned short* VtG = (unsigned short*)(ws + 33554432);
  unsigned short* Y = (unsigned short*)(ws + 50331648);
  unsigned short* xb = Y;
  unsigned short* Wqb = (unsigned short*)(ws + 67108864);
  unsigned short* Wpb = (unsigned short*)(ws + 92274688);
  float2* tab = (float2*)(ws + 100663296);

  cvt_bf16_k<<<4096, 256, 0, stream>>>(x, xb, 1048576);
  cvt_bf16_k<<<6144, 256, 0, stream>>>(Wq, Wqb, 1572864);
  cvt_bf16_k<<<2048, 256, 0, stream>>>(Wp, Wpb, 524288);
  rope_tab<<<512, 256, 0, stream>>>(tab);
  gemm_bf<1><<<dim3(48, 32), 256, 0, stream>>>(xb, Wqb, qkv16, VtG, 4096, 6144,
                                               2048);
  rms_rope<<<4096, 256, 0, stream>>>(qkv16, g, tab);
  attn64<<<1024, 256, 0, stream>>>(qkv16, VtG, Y);  // overwrites xb (dead)
  gemm_bf<0><<<dim3(16, 32), 256, 0, stream>>>(Y, Wpb, out, nullptr, 4096, 2048,
                                               2048);
}